// Round 3
// baseline (968.326 us; speedup 1.0000x reference)
//
#include <hip/hip_runtime.h>
#include <cstddef>
#include <cstdint>

// Problem constants
#define NB_ 4
#define N_ 4096
#define D_ 1024
#define H_ 16
#define DH_ 64
#define PD_ 8
#define PS_ 4
#define F_ 72               // DH + PD
#define NCHUNK 16
#define NPC (N_ / NCHUNK)   // 256 rows per ctx chunk
#define SLOT_ (F_ * DH_ + F_)   // 4680 floats per partial slot

typedef __attribute__((ext_vector_type(8))) short short8;
typedef __attribute__((ext_vector_type(4))) float f32x4;
typedef __attribute__((ext_vector_type(8))) unsigned short ushort8;

__device__ __forceinline__ unsigned short f2bf(float f) {
  uint32_t u = __builtin_bit_cast(uint32_t, f);
  u += 0x7FFFu + ((u >> 16) & 1u);          // RTNE
  return (unsigned short)(u >> 16);
}
__device__ __forceinline__ float bf2f(unsigned short h) {
  uint32_t u = ((uint32_t)h) << 16;
  return __builtin_bit_cast(float, u);
}

__device__ __forceinline__ void gload16(const void* g, void* l) {
  __builtin_amdgcn_global_load_lds((const __attribute__((address_space(1))) void*)g,
                                   (__attribute__((address_space(3))) void*)l, 16, 0, 0);
}

// ---------------- f32 -> bf16 conversion kernels -----------------------------
__global__ __launch_bounds__(256) void convert_x_kernel(
    const float* __restrict__ in, unsigned short* __restrict__ out)
{
  const int i = blockIdx.x * 256 + threadIdx.x;   // 8-elem group index
  const float4* p = (const float4*)in + (size_t)i * 2;
  const float4 a = p[0], b = p[1];
  ushort8 o;
  o[0] = f2bf(a.x); o[1] = f2bf(a.y); o[2] = f2bf(a.z); o[3] = f2bf(a.w);
  o[4] = f2bf(b.x); o[5] = f2bf(b.y); o[6] = f2bf(b.z); o[7] = f2bf(b.w);
  *(ushort8*)(out + (size_t)i * 8) = o;
}

// Wc rows: [0,1024)=Wq, [1024,2048)=Wk, [2048,3072)=Wv, [3072,4096)=Wo
__global__ __launch_bounds__(256) void convert_w_kernel(
    const float* __restrict__ Wq, const float* __restrict__ Wk,
    const float* __restrict__ Wv, const float* __restrict__ Wo,
    unsigned short* __restrict__ Wc)
{
  const int i = blockIdx.x * 256 + threadIdx.x;
  const size_t off = (size_t)i * 8;
  const float* src;
  if (off < (size_t)1048576)      src = Wq + off;
  else if (off < (size_t)2097152) src = Wk + (off - 1048576);
  else if (off < (size_t)3145728) src = Wv + (off - 2097152);
  else                            src = Wo + (off - 3145728);
  const float4 a = ((const float4*)src)[0], b = ((const float4*)src)[1];
  ushort8 o;
  o[0] = f2bf(a.x); o[1] = f2bf(a.y); o[2] = f2bf(a.z); o[3] = f2bf(a.w);
  o[4] = f2bf(b.x); o[5] = f2bf(b.y); o[6] = f2bf(b.z); o[7] = f2bf(b.w);
  *(ushort8*)(Wc + off) = o;
}

// ---------------- bf16 MFMA GEMM: C = A @ W^T (+ bias) -----------------------
// A: [M x K] bf16 row-major (row stride lda elems); W: [Ntot x K] bf16 row-major.
// Tile 128x128, BK=64, 256 threads = 4 waves in 2x2; each wave owns 64x64.
// LDS tiles [128 rows][8 kslots of 16B], XOR-swizzled: slot(row,ks) stored at
// linear slot row*8 + (ks ^ (row&7)); staging pre-applies the inverse on the
// GLOBAL source address (global_load_lds dest must be linear, rule 21).
// OUTMODE 0: bf16 output.  OUTMODE 1: f32 output + bias[col].
template <int OUTMODE>
__global__ __launch_bounds__(256) void gemm_bf16_kernel(
    const unsigned short* __restrict__ A, int lda,
    const unsigned short* __restrict__ Wt,
    const float* __restrict__ bias,
    void* __restrict__ Cout, int ldc, int K)
{
  __shared__ unsigned short lds[2 * 128 * 64];   // A tile [0,8192), B tile [8192,16384)
  const int tid = threadIdx.x;
  const int lane = tid & 63;
  const int w = tid >> 6;
  const int wr = w >> 1, wc = w & 1;
  const int m0 = blockIdx.y * 128;
  const int j0 = blockIdx.x * 128;

  // Staging source pointers (inverse-swizzled k-slot per linear LDS slot).
  const unsigned short* aSrc[4];
  const unsigned short* bSrc[4];
#pragma unroll
  for (int it = 0; it < 4; ++it) {
    const int u = it * 256 + tid;      // linear 16B slot in tile
    const int row = u >> 3, c = u & 7;
    const int ks = c ^ (row & 7);
    aSrc[it] = A  + (size_t)(m0 + row) * lda + ks * 8;
    bSrc[it] = Wt + (size_t)(j0 + row) * K   + ks * 8;
  }

  // Swizzled read offsets (ushort units) for MFMA fragments.
  int aoff[4][2], boff[4][2];
#pragma unroll
  for (int m = 0; m < 4; ++m) {
#pragma unroll
    for (int s = 0; s < 2; ++s) {
      const int kslot = s * 4 + (lane >> 4);
      const int ra = wr * 64 + m * 16 + (lane & 15);
      aoff[m][s] = (ra * 8 + (kslot ^ (ra & 7))) * 8;
      const int rb = wc * 64 + m * 16 + (lane & 15);
      boff[m][s] = 8192 + (rb * 8 + (kslot ^ (rb & 7))) * 8;
    }
  }

  f32x4 acc[4][4];
#pragma unroll
  for (int m = 0; m < 4; ++m)
#pragma unroll
    for (int n = 0; n < 4; ++n) acc[m][n] = {0.f, 0.f, 0.f, 0.f};

  for (int k0 = 0; k0 < K; k0 += 64) {
    __syncthreads();   // previous tile's readers done
#pragma unroll
    for (int it = 0; it < 4; ++it) {
      gload16(aSrc[it] + k0, (void*)&lds[(size_t)(it * 256 + w * 64) * 8]);
      gload16(bSrc[it] + k0, (void*)&lds[8192 + (size_t)(it * 256 + w * 64) * 8]);
    }
    __syncthreads();   // drains vmcnt(0): tile resident
#pragma unroll
    for (int s = 0; s < 2; ++s) {
      short8 af[4], bfr[4];
#pragma unroll
      for (int m = 0; m < 4; ++m) af[m] = *(const short8*)&lds[aoff[m][s]];
#pragma unroll
      for (int n = 0; n < 4; ++n) bfr[n] = *(const short8*)&lds[boff[n][s]];
#pragma unroll
      for (int m = 0; m < 4; ++m)
#pragma unroll
        for (int n = 0; n < 4; ++n)
          acc[m][n] = __builtin_amdgcn_mfma_f32_16x16x32_bf16(af[m], bfr[n], acc[m][n], 0, 0, 0);
    }
  }

  // Epilogue. C/D layout (m89-verified): row=(lane>>4)*4+reg, col=lane&15.
  const int rbase = (lane >> 4) * 4;
  const int cbase = lane & 15;
#pragma unroll
  for (int m = 0; m < 4; ++m) {
#pragma unroll
    for (int n = 0; n < 4; ++n) {
      const int col = j0 + wc * 64 + n * 16 + cbase;
      const float bj = (OUTMODE == 1) ? bias[col] : 0.f;
#pragma unroll
      for (int r = 0; r < 4; ++r) {
        const int rowi = m0 + wr * 64 + m * 16 + rbase + r;
        if (OUTMODE == 0)
          ((unsigned short*)Cout)[(size_t)rowi * ldc + col] = f2bf(acc[m][n][r]);
        else
          ((float*)Cout)[(size_t)rowi * ldc + col] = acc[m][n][r] + bj;
      }
    }
  }
}

// ---------- ctx partial: per (h,chunk) accumulate exp(k)^T @ v and colsum ----
// QKV: [4096, 3072] bf16 = [Q' | K' | V'] (pre-bias).
// kraw[n,d<64] = K'[n,h*64+d] + bk[h,d];  kraw[n,64+p] = posb[n,p] + bk[h,64+p]
// v[n,e] = V'[n,h*64+e] + bv[h*64+e]
__global__ __launch_bounds__(256) void ctx_partial_kernel(
    const unsigned short* __restrict__ QKV, const float* __restrict__ posb,
    const float* __restrict__ bk, const float* __restrict__ bv,
    float* __restrict__ partial)
{
  const int h = blockIdx.y, ch = blockIdx.x;
  const int tid = threadIdx.x;
  __shared__ float kbuf[16][F_];
  __shared__ float vbuf[16][DH_];

  const int e = tid & 63;
  const int dslot = tid >> 6;  // 0..3
  float acc[18];
#pragma unroll
  for (int j = 0; j < 18; ++j) acc[j] = 0.f;
  float csum = 0.f;

  const int n0 = ch * NPC;
  for (int t0 = 0; t0 < NPC; t0 += 16) {
    const int row0 = n0 + t0;
    __syncthreads();
    for (int idx = tid; idx < 16 * 64; idx += 256) {
      const int r = idx >> 6, d = idx & 63;
      const size_t base = (size_t)(row0 + r) * 3072;
      kbuf[r][d] = __expf(bf2f(QKV[base + 1024 + h * 64 + d]) + bk[h * F_ + d]);
      vbuf[r][d] = bf2f(QKV[base + 2048 + h * 64 + d]) + bv[h * 64 + d];
    }
    if (tid < 16 * PD_) {
      const int r = tid >> 3, p = tid & 7;
      kbuf[r][64 + p] = __expf(posb[(size_t)(row0 + r) * PD_ + p] + bk[h * F_ + 64 + p]);
    }
    __syncthreads();
#pragma unroll
    for (int r = 0; r < 16; ++r) {
      const float ve = vbuf[r][e];
#pragma unroll
      for (int j = 0; j < 18; ++j) acc[j] += kbuf[r][dslot + 4 * j] * ve;
    }
    if (tid < F_) {
#pragma unroll
      for (int r = 0; r < 16; ++r) csum += kbuf[r][tid];
    }
  }

  float* pp = partial + (size_t)(h * NCHUNK + ch) * SLOT_;
#pragma unroll
  for (int j = 0; j < 18; ++j) pp[(dslot + 4 * j) * 64 + e] = acc[j];
  if (tid < F_) pp[F_ * DH_ + tid] = csum;
}

// ---------- attention out: ctx reduce + q assembly + softmax + q @ ctx -------
// out[n,e] = (sum_d exp(q_d) * ctx[d][e]) / sum_d exp(q_d)   (d_inv == 1)
__global__ __launch_bounds__(256) void attn_out_kernel(
    const unsigned short* __restrict__ QKV, const float* __restrict__ posb,
    const float* __restrict__ alpha, const float* __restrict__ beta,
    const float* __restrict__ bq, const float* __restrict__ partial,
    unsigned short* __restrict__ attnb)
{
  const int h = blockIdx.y, ch = blockIdx.x;
  const int tid = threadIdx.x;
  __shared__ float ctxs[F_][DH_];
  __shared__ float cinv[F_];
  __shared__ float qbuf[16][F_];
  __shared__ float qinv[16];
  __shared__ float bqs[F_];

  // Reduce column-softmax denominators, then ctx (normalized).
  if (tid < F_) {
    float s = 0.f;
    for (int c = 0; c < NCHUNK; ++c)
      s += partial[(size_t)(h * NCHUNK + c) * SLOT_ + F_ * DH_ + tid];
    cinv[tid] = 1.0f / s;
    bqs[tid] = bq[h * F_ + tid];
  }
  __syncthreads();
  for (int idx = tid; idx < F_ * DH_; idx += 256) {
    float s = 0.f;
    for (int c = 0; c < NCHUNK; ++c)
      s += partial[(size_t)(h * NCHUNK + c) * SLOT_ + idx];
    ctxs[idx >> 6][idx & 63] = s * cinv[idx >> 6];
  }
  __syncthreads();

  const int e = tid & 63;
  const int rslot = tid >> 6;  // 0..3
  const int n0 = ch * 256;

  for (int t0 = 0; t0 < 256; t0 += 16) {
    const int row0 = n0 + t0;
    __syncthreads();  // protect qbuf/qinv from previous iteration's readers
    for (int idx = tid; idx < 16 * 64; idx += 256) {
      const int r = idx >> 6, d = idx & 63;
      qbuf[r][d] = __expf(bf2f(QKV[(size_t)(row0 + r) * 3072 + h * 64 + d]) + bqs[d]);
    }
    if (tid < 16 * PS_) {  // 64 threads: one (row, rotation-block) each
      const int r = tid >> 2, s = tid & 3;
      const float p0 = posb[(size_t)(row0 + r) * PD_ + 2 * s];
      const float p1 = posb[(size_t)(row0 + r) * PD_ + 2 * s + 1];
      const float al = alpha[h * PS_ + s], be = beta[h * PS_ + s];
      qbuf[r][64 + 2 * s]     = __expf(al * p0 - be * p1 + bqs[64 + 2 * s]);
      qbuf[r][64 + 2 * s + 1] = __expf(be * p0 + al * p1 + bqs[64 + 2 * s + 1]);
    }
    __syncthreads();
    if (tid < 16) {
      float s = 0.f;
#pragma unroll
      for (int d = 0; d < F_; ++d) s += qbuf[tid][d];
      qinv[tid] = 1.0f / s;
    }
    __syncthreads();
#pragma unroll
    for (int rr = 0; rr < 16; rr += 4) {
      const int r = rslot + rr;
      float o = 0.f;
#pragma unroll
      for (int d = 0; d < F_; ++d) o += qbuf[r][d] * ctxs[d][e];
      attnb[(size_t)(row0 + r) * D_ + h * 64 + e] = f2bf(o * qinv[r]);
    }
  }
}

// ------------------------------ launch ---------------------------------------
extern "C" void kernel_launch(void* const* d_in, const int* in_sizes, int n_in,
                              void* d_out, int out_size, void* d_ws, size_t ws_size,
                              hipStream_t stream) {
  const float* x     = (const float*)d_in[0];
  const float* pos   = (const float*)d_in[1];
  const float* Wq    = (const float*)d_in[2];
  const float* alpha = (const float*)d_in[3];
  const float* beta  = (const float*)d_in[4];
  const float* bq    = (const float*)d_in[5];
  const float* Wk    = (const float*)d_in[6];
  const float* bk    = (const float*)d_in[7];
  const float* Wv    = (const float*)d_in[8];
  const float* bv    = (const float*)d_in[9];
  const float* Wo    = (const float*)d_in[10];
  const float* bo    = (const float*)d_in[11];
  float* out = (float*)d_out;

  // Workspace layout (bytes) — total ~52.6 MB
  const size_t OFF_WC   = 0;                        // [4096][1024] bf16 (Wq|Wk|Wv|Wo)
  const size_t SZ_WC    = (size_t)4096 * 1024 * 2;  // 8,388,608
  const size_t OFF_XB   = OFF_WC + SZ_WC;           // [4096][1024] bf16
  const size_t SZ_XB    = (size_t)N_ * D_ * 2;
  const size_t OFF_QKV  = OFF_XB + SZ_XB;           // [4096][3072] bf16
  const size_t SZ_QKV   = (size_t)N_ * 3072 * 2;
  const size_t OFF_ATT  = OFF_QKV + SZ_QKV;         // [4096][1024] bf16
  const size_t SZ_ATT   = (size_t)N_ * D_ * 2;
  const size_t OFF_PART = OFF_ATT + SZ_ATT;         // f32 partials
  const size_t SZ_PART  = (size_t)H_ * NCHUNK * SLOT_ * sizeof(float);
  if (ws_size < OFF_PART + SZ_PART) return;

  char* ws = (char*)d_ws;
  unsigned short* Wc      = (unsigned short*)(ws + OFF_WC);
  unsigned short* Woc     = Wc + (size_t)3072 * 1024;
  unsigned short* xb      = (unsigned short*)(ws + OFF_XB);
  unsigned short* QKVb    = (unsigned short*)(ws + OFF_QKV);
  unsigned short* attnb   = (unsigned short*)(ws + OFF_ATT);
  float*          partial = (float*)(ws + OFF_PART);

  const dim3 blk(256);
  convert_w_kernel<<<dim3(2048), blk, 0, stream>>>(Wq, Wk, Wv, Wo, Wc);

  for (int b = 0; b < NB_; ++b) {
    const float* xbp  = x   + (size_t)b * N_ * D_;
    const float* posb = pos + (size_t)b * N_ * PD_;
    float*       outb = out + (size_t)b * N_ * D_;

    // x -> bf16
    convert_x_kernel<<<dim3(2048), blk, 0, stream>>>(xbp, xb);
    // QKV' = xb @ [Wq;Wk;Wv]^T   [4096 x 3072] bf16
    gemm_bf16_kernel<0><<<dim3(3072 / 128, N_ / 128), blk, 0, stream>>>(
        xb, D_, Wc, nullptr, QKVb, 3072, D_);
    // partial ctx + column-softmax denominators
    ctx_partial_kernel<<<dim3(NCHUNK, H_), blk, 0, stream>>>(QKVb, posb, bk, bv, partial);
    // ctx reduce + q softmax + q @ ctx -> attnb bf16
    attn_out_kernel<<<dim3(N_ / 256, H_), blk, 0, stream>>>(
        QKVb, posb, alpha, beta, bq, partial, attnb);
    // out = attnb @ Wo^T + bo   (f32)
    gemm_bf16_kernel<1><<<dim3(1024 / 128, N_ / 128), blk, 0, stream>>>(
        attnb, D_, Woc, bo, outb, D_, D_);
  }
}

// Round 4
// 655.150 us; speedup vs baseline: 1.4780x; 1.4780x over previous
//
#include <hip/hip_runtime.h>
#include <cstddef>
#include <cstdint>

// Problem constants
#define NB_ 4
#define N_ 4096
#define D_ 1024
#define H_ 16
#define DH_ 64
#define PD_ 8
#define PS_ 4
#define F_ 72               // DH + PD
#define FPAD_ 96            // K-padded F (3 x 32 MFMA k-steps)
#define LST_ 104            // LDS/global row stride for P and ctx_t (bank-friendly)
#define CTROWS_ 80          // ctx_t rows: 64 e + 1 ones + 15 zero
#define CTSZ_ (CTROWS_ * LST_)   // 8320 ushorts per (head) ctx_t
#define SLOT_ (F_ * DH_ + F_)    // 4680 floats per partial slot

typedef __attribute__((ext_vector_type(8))) short short8;
typedef __attribute__((ext_vector_type(4))) float f32x4;
typedef __attribute__((ext_vector_type(8))) unsigned short ushort8;

__device__ __forceinline__ unsigned short f2bf(float f) {
  uint32_t u = __builtin_bit_cast(uint32_t, f);
  u += 0x7FFFu + ((u >> 16) & 1u);          // RTNE
  return (unsigned short)(u >> 16);
}
__device__ __forceinline__ float bf2f(unsigned short h) {
  uint32_t u = ((uint32_t)h) << 16;
  return __builtin_bit_cast(float, u);
}

__device__ __forceinline__ void gload16(const void* g, void* l) {
  __builtin_amdgcn_global_load_lds((const __attribute__((address_space(1))) void*)g,
                                   (__attribute__((address_space(3))) void*)l, 16, 0, 0);
}

// ---------------- f32 -> bf16 conversion kernels -----------------------------
__global__ __launch_bounds__(256) void convert_x_kernel(
    const float* __restrict__ in, unsigned short* __restrict__ out)
{
  const int i = blockIdx.x * 256 + threadIdx.x;   // 8-elem group index
  const float4* p = (const float4*)in + (size_t)i * 2;
  const float4 a = p[0], b = p[1];
  ushort8 o;
  o[0] = f2bf(a.x); o[1] = f2bf(a.y); o[2] = f2bf(a.z); o[3] = f2bf(a.w);
  o[4] = f2bf(b.x); o[5] = f2bf(b.y); o[6] = f2bf(b.z); o[7] = f2bf(b.w);
  *(ushort8*)(out + (size_t)i * 8) = o;
}

// Wc rows: [0,1024)=Wq, [1024,2048)=Wk, [2048,3072)=Wv, [3072,4096)=Wo
__global__ __launch_bounds__(256) void convert_w_kernel(
    const float* __restrict__ Wq, const float* __restrict__ Wk,
    const float* __restrict__ Wv, const float* __restrict__ Wo,
    unsigned short* __restrict__ Wc)
{
  const int i = blockIdx.x * 256 + threadIdx.x;
  const size_t off = (size_t)i * 8;
  const float* src;
  if (off < (size_t)1048576)      src = Wq + off;
  else if (off < (size_t)2097152) src = Wk + (off - 1048576);
  else if (off < (size_t)3145728) src = Wv + (off - 2097152);
  else                            src = Wo + (off - 3145728);
  const float4 a = ((const float4*)src)[0], b = ((const float4*)src)[1];
  ushort8 o;
  o[0] = f2bf(a.x); o[1] = f2bf(a.y); o[2] = f2bf(a.z); o[3] = f2bf(a.w);
  o[4] = f2bf(b.x); o[5] = f2bf(b.y); o[6] = f2bf(b.z); o[7] = f2bf(b.w);
  *(ushort8*)(Wc + off) = o;
}

// ---------------- bf16 MFMA GEMM: C = A @ W^T (+ bias) -----------------------
// (unchanged from round 3 — hardware-verified)
template <int OUTMODE>
__global__ __launch_bounds__(256) void gemm_bf16_kernel(
    const unsigned short* __restrict__ A, int lda,
    const unsigned short* __restrict__ Wt,
    const float* __restrict__ bias,
    void* __restrict__ Cout, int ldc, int K)
{
  __shared__ unsigned short lds[2 * 128 * 64];   // A tile [0,8192), B tile [8192,16384)
  const int tid = threadIdx.x;
  const int lane = tid & 63;
  const int w = tid >> 6;
  const int wr = w >> 1, wc = w & 1;
  const int m0 = blockIdx.y * 128;
  const int j0 = blockIdx.x * 128;

  const unsigned short* aSrc[4];
  const unsigned short* bSrc[4];
#pragma unroll
  for (int it = 0; it < 4; ++it) {
    const int u = it * 256 + tid;      // linear 16B slot in tile
    const int row = u >> 3, c = u & 7;
    const int ks = c ^ (row & 7);
    aSrc[it] = A  + (size_t)(m0 + row) * lda + ks * 8;
    bSrc[it] = Wt + (size_t)(j0 + row) * K   + ks * 8;
  }

  int aoff[4][2], boff[4][2];
#pragma unroll
  for (int m = 0; m < 4; ++m) {
#pragma unroll
    for (int s = 0; s < 2; ++s) {
      const int kslot = s * 4 + (lane >> 4);
      const int ra = wr * 64 + m * 16 + (lane & 15);
      aoff[m][s] = (ra * 8 + (kslot ^ (ra & 7))) * 8;
      const int rb = wc * 64 + m * 16 + (lane & 15);
      boff[m][s] = 8192 + (rb * 8 + (kslot ^ (rb & 7))) * 8;
    }
  }

  f32x4 acc[4][4];
#pragma unroll
  for (int m = 0; m < 4; ++m)
#pragma unroll
    for (int n = 0; n < 4; ++n) acc[m][n] = {0.f, 0.f, 0.f, 0.f};

  for (int k0 = 0; k0 < K; k0 += 64) {
    __syncthreads();
#pragma unroll
    for (int it = 0; it < 4; ++it) {
      gload16(aSrc[it] + k0, (void*)&lds[(size_t)(it * 256 + w * 64) * 8]);
      gload16(bSrc[it] + k0, (void*)&lds[8192 + (size_t)(it * 256 + w * 64) * 8]);
    }
    __syncthreads();
#pragma unroll
    for (int s = 0; s < 2; ++s) {
      short8 af[4], bfr[4];
#pragma unroll
      for (int m = 0; m < 4; ++m) af[m] = *(const short8*)&lds[aoff[m][s]];
#pragma unroll
      for (int n = 0; n < 4; ++n) bfr[n] = *(const short8*)&lds[boff[n][s]];
#pragma unroll
      for (int m = 0; m < 4; ++m)
#pragma unroll
        for (int n = 0; n < 4; ++n)
          acc[m][n] = __builtin_amdgcn_mfma_f32_16x16x32_bf16(af[m], bfr[n], acc[m][n], 0, 0, 0);
    }
  }

  const int rbase = (lane >> 4) * 4;
  const int cbase = lane & 15;
#pragma unroll
  for (int m = 0; m < 4; ++m) {
#pragma unroll
    for (int n = 0; n < 4; ++n) {
      const int col = j0 + wc * 64 + n * 16 + cbase;
      const float bj = (OUTMODE == 1) ? bias[col] : 0.f;
#pragma unroll
      for (int r = 0; r < 4; ++r) {
        const int rowi = m0 + wr * 64 + m * 16 + rbase + r;
        if (OUTMODE == 0)
          ((unsigned short*)Cout)[(size_t)rowi * ldc + col] = f2bf(acc[m][n][r]);
        else
          ((float*)Cout)[(size_t)rowi * ldc + col] = acc[m][n][r] + bj;
      }
    }
  }
}

// ---------- ctx via MFMA: per (h,chunk) partial [Kexp^T @ V | colsum] --------
// A-frag (d-dim x n): per-lane global loads of K' (exp'd in-register) / pos.
// B-frag (e-dim x n): per-lane global loads of raw V' bf16 (bv folded later).
// Col-tile 4 = synthesized ones column -> colsum (same rounded kexp as num).
__global__ __launch_bounds__(256) void ctx_mfma_kernel(
    const unsigned short* __restrict__ QKV, const float* __restrict__ posb,
    const float* __restrict__ bk, float* __restrict__ partial)
{
  const int h = blockIdx.y, ch = blockIdx.x;
  const int tid = threadIdx.x;
  const int w = tid >> 6, lane = tid & 63;
  const int g = lane >> 4, c15 = lane & 15;
  const int n0 = ch * 256 + w * 64;

  f32x4 acc[5][5];
#pragma unroll
  for (int dt = 0; dt < 5; ++dt)
#pragma unroll
    for (int ct = 0; ct < 5; ++ct) acc[dt][ct] = {0.f, 0.f, 0.f, 0.f};

  for (int kc = 0; kc < 2; ++kc) {
    const int nb = n0 + kc * 32 + g * 8;        // this lane's first n-row (j adds 0..7)
    const size_t rowb = (size_t)nb * 3072;

    short8 bf4[4];
#pragma unroll
    for (int et = 0; et < 4; ++et) {
      const unsigned short* vp = QKV + rowb + 2048 + h * 64 + et * 16 + c15;
      ushort8 t;
#pragma unroll
      for (int j = 0; j < 8; ++j) t[j] = vp[(size_t)j * 3072];
      bf4[et] = __builtin_bit_cast(short8, t);
    }
    ushort8 ot;
    const unsigned short one = (c15 == 0) ? (unsigned short)0x3F80 : (unsigned short)0;
#pragma unroll
    for (int j = 0; j < 8; ++j) ot[j] = one;
    const short8 onesf = __builtin_bit_cast(short8, ot);

#pragma unroll
    for (int dt = 0; dt < 5; ++dt) {
      const int d = dt * 16 + c15;
      ushort8 at;
      if (dt < 4) {                              // content dims: K' + bk, exp
        const float bkd = bk[h * F_ + d];
        const unsigned short* kp = QKV + rowb + 1024 + h * 64 + d;
#pragma unroll
        for (int j = 0; j < 8; ++j) at[j] = f2bf(__expf(bf2f(kp[(size_t)j * 3072]) + bkd));
      } else if (d < 72) {                       // pos dims: raw pos + bk, exp
        const float bkd = bk[h * F_ + d];
        const float* pp = posb + (size_t)nb * PD_ + (d - 64);
#pragma unroll
        for (int j = 0; j < 8; ++j) at[j] = f2bf(__expf(pp[(size_t)j * PD_] + bkd));
      } else {                                   // zero pad rows
#pragma unroll
        for (int j = 0; j < 8; ++j) at[j] = 0;
      }
      const short8 af = __builtin_bit_cast(short8, at);
#pragma unroll
      for (int ct = 0; ct < 4; ++ct)
        acc[dt][ct] = __builtin_amdgcn_mfma_f32_16x16x32_bf16(af, bf4[ct], acc[dt][ct], 0, 0, 0);
      acc[dt][4] = __builtin_amdgcn_mfma_f32_16x16x32_bf16(af, onesf, acc[dt][4], 0, 0, 0);
    }
  }

  // Cross-wave reduce in LDS. D-layout: row = dt*16 + g*4 + r, col = ct*16 + c15.
  __shared__ float red[80 * 80];
  const int rb = g * 4;
  for (int ww = 0; ww < 4; ++ww) {
    if (w == ww) {
#pragma unroll
      for (int dt = 0; dt < 5; ++dt)
#pragma unroll
        for (int ct = 0; ct < 5; ++ct)
#pragma unroll
          for (int r = 0; r < 4; ++r) {
            const int idx = (dt * 16 + rb + r) * 80 + ct * 16 + c15;
            if (ww == 0) red[idx] = acc[dt][ct][r];
            else         red[idx] += acc[dt][ct][r];
          }
    }
    __syncthreads();
  }
  float* pp = partial + (size_t)(h * 16 + ch) * SLOT_;
  for (int idx = tid; idx < SLOT_; idx += 256)
    pp[idx] = (idx < 4608) ? red[(idx >> 6) * 80 + (idx & 63)]
                           : red[(idx - 4608) * 80 + 64];
}

// ---------- ctx finalize: reduce chunks, /colsum, +bv, transpose, bf16 -------
// Writes ctx_t[h][e][d] with row 64 = ones (for qsum), zero pads elsewhere.
__global__ __launch_bounds__(256) void ctx_finalize_kernel(
    const float* __restrict__ partial, const float* __restrict__ bv,
    unsigned short* __restrict__ ctxt)
{
  const int h = blockIdx.x;
  const int tid = threadIdx.x;
  __shared__ float num[F_ * DH_];
  __shared__ float cinv[F_];
  for (int idx = tid; idx < F_ * DH_; idx += 256) {
    float s = 0.f;
    for (int c = 0; c < 16; ++c) s += partial[(size_t)(h * 16 + c) * SLOT_ + idx];
    num[idx] = s;
  }
  if (tid < F_) {
    float s = 0.f;
    for (int c = 0; c < 16; ++c) s += partial[(size_t)(h * 16 + c) * SLOT_ + F_ * DH_ + tid];
    cinv[tid] = 1.0f / s;
  }
  __syncthreads();
  unsigned short* cp = ctxt + (size_t)h * CTSZ_;
  for (int j = tid; j < CTSZ_; j += 256) {
    const int e = j / LST_, d = j - e * LST_;
    float v = 0.f;
    if (e < 64)       { if (d < F_) v = num[d * 64 + e] * cinv[d] + bv[h * 64 + e]; }
    else if (e == 64) { if (d < F_) v = 1.0f; }
    cp[j] = f2bf(v);
  }
}

// ---------- attention out via MFMA: P[64 x 96] @ ctx_t^T, qsum via ones-row --
// Writes result into QKV's dead V' slots (cols [2048,3072)).
__global__ __launch_bounds__(256) void attn_mfma_kernel(
    unsigned short* __restrict__ QKV, const float* __restrict__ posb,
    const float* __restrict__ alpha, const float* __restrict__ beta,
    const float* __restrict__ bq, const unsigned short* __restrict__ ctxt)
{
  const int h = blockIdx.y;
  const int n0 = blockIdx.x * 64;
  const int tid = threadIdx.x;
  __shared__ unsigned short P[64 * LST_];
  __shared__ unsigned short CT[CTROWS_ * LST_];
  __shared__ float bqs[F_];

  const unsigned short* cg = ctxt + (size_t)h * CTSZ_;
  for (int idx = tid; idx < CTSZ_ / 8; idx += 256)
    *(ushort8*)&CT[idx * 8] = *(const ushort8*)&cg[idx * 8];
  if (tid < F_) bqs[tid] = bq[h * F_ + tid];
  __syncthreads();

  {  // build P: exp(q + bq) in bf16; rows = tokens, cols = d (96 zero-padded)
    const int row = tid >> 2, q4 = tid & 3;
    const unsigned short* qp = QKV + (size_t)(n0 + row) * 3072 + h * 64 + q4 * 16;
    const ushort8 a = *(const ushort8*)qp;
    const ushort8 b = *(const ushort8*)(qp + 8);
    ushort8 oa, ob;
#pragma unroll
    for (int j = 0; j < 8; ++j) {
      oa[j] = f2bf(__expf(bf2f(a[j]) + bqs[q4 * 16 + j]));
      ob[j] = f2bf(__expf(bf2f(b[j]) + bqs[q4 * 16 + 8 + j]));
    }
    *(ushort8*)&P[row * LST_ + q4 * 16] = oa;
    *(ushort8*)&P[row * LST_ + q4 * 16 + 8] = ob;
    // pos rotation pair s = q4
    const float p0 = posb[(size_t)(n0 + row) * PD_ + 2 * q4];
    const float p1 = posb[(size_t)(n0 + row) * PD_ + 2 * q4 + 1];
    const float al = alpha[h * PS_ + q4], be = beta[h * PS_ + q4];
    P[row * LST_ + 64 + 2 * q4]     = f2bf(__expf(al * p0 - be * p1 + bqs[64 + 2 * q4]));
    P[row * LST_ + 64 + 2 * q4 + 1] = f2bf(__expf(be * p0 + al * p1 + bqs[64 + 2 * q4 + 1]));
#pragma unroll
    for (int jj = 0; jj < 6; ++jj) P[row * LST_ + 72 + q4 * 6 + jj] = 0;  // k-pad
  }
  __syncthreads();

  const int w = tid >> 6, lane = tid & 63;
  const int g = lane >> 4, c15 = lane & 15;
  f32x4 acc[5];
#pragma unroll
  for (int ct = 0; ct < 5; ++ct) acc[ct] = {0.f, 0.f, 0.f, 0.f};
  short8 af[3];
#pragma unroll
  for (int ks = 0; ks < 3; ++ks)
    af[ks] = *(const short8*)&P[(w * 16 + c15) * LST_ + ks * 32 + g * 8];
#pragma unroll
  for (int ct = 0; ct < 5; ++ct) {
#pragma unroll
    for (int ks = 0; ks < 3; ++ks) {
      const short8 bfr = *(const short8*)&CT[(ct * 16 + c15) * LST_ + ks * 32 + g * 8];
      acc[ct] = __builtin_amdgcn_mfma_f32_16x16x32_bf16(af[ks], bfr, acc[ct], 0, 0, 0);
    }
  }
  // qsum lives in col-tile 4, col 64 (lanes with c15==0), rows g*4+r.
  float qinv[4];
#pragma unroll
  for (int r = 0; r < 4; ++r) {
    const float qs = __shfl(acc[4][r], lane & 48);
    qinv[r] = 1.0f / qs;
  }
#pragma unroll
  for (int ct = 0; ct < 4; ++ct) {
#pragma unroll
    for (int r = 0; r < 4; ++r) {
      const int rowi = n0 + w * 16 + g * 4 + r;
      QKV[(size_t)rowi * 3072 + 2048 + h * 64 + ct * 16 + c15] = f2bf(acc[ct][r] * qinv[r]);
    }
  }
}

// ------------------------------ launch ---------------------------------------
extern "C" void kernel_launch(void* const* d_in, const int* in_sizes, int n_in,
                              void* d_out, int out_size, void* d_ws, size_t ws_size,
                              hipStream_t stream) {
  const float* x     = (const float*)d_in[0];
  const float* pos   = (const float*)d_in[1];
  const float* Wq    = (const float*)d_in[2];
  const float* alpha = (const float*)d_in[3];
  const float* beta  = (const float*)d_in[4];
  const float* bq    = (const float*)d_in[5];
  const float* Wk    = (const float*)d_in[6];
  const float* bk    = (const float*)d_in[7];
  const float* Wv    = (const float*)d_in[8];
  const float* bv    = (const float*)d_in[9];
  const float* Wo    = (const float*)d_in[10];
  const float* bo    = (const float*)d_in[11];
  float* out = (float*)d_out;

  // Workspace (bytes), total 47,001,600 — under round-3's proven 52.7 MB floor.
  const size_t OFF_WC   = 0;                         // [4096][1024] bf16 (Wq|Wk|Wv|Wo)
  const size_t SZ_WC    = (size_t)4096 * 1024 * 2;
  const size_t OFF_XB   = OFF_WC + SZ_WC;            // [4096][1024] bf16 (per batch)
  const size_t SZ_XB    = (size_t)N_ * D_ * 2;
  const size_t OFF_QKV  = OFF_XB + SZ_XB;            // [4096][3072] bf16 (per batch)
  const size_t SZ_QKV   = (size_t)N_ * 3072 * 2;
  const size_t OFF_PART = OFF_QKV + SZ_QKV;          // f32 partials
  const size_t SZ_PART  = (size_t)H_ * 16 * SLOT_ * sizeof(float);
  const size_t OFF_CT   = OFF_PART + SZ_PART;        // ctx_t bf16 [16][80][104]
  const size_t SZ_CT    = (size_t)H_ * CTSZ_ * 2;
  if (ws_size < OFF_CT + SZ_CT) return;

  char* ws = (char*)d_ws;
  unsigned short* Wc      = (unsigned short*)(ws + OFF_WC);
  unsigned short* Woc     = Wc + (size_t)3072 * 1024;
  unsigned short* xb      = (unsigned short*)(ws + OFF_XB);
  unsigned short* QKVb    = (unsigned short*)(ws + OFF_QKV);
  float*          partial = (float*)(ws + OFF_PART);
  unsigned short* ctxt    = (unsigned short*)(ws + OFF_CT);

  const dim3 blk(256);
  convert_w_kernel<<<dim3(2048), blk, 0, stream>>>(Wq, Wk, Wv, Wo, Wc);

  for (int b = 0; b < NB_; ++b) {
    const float* xbp  = x   + (size_t)b * N_ * D_;
    const float* posb = pos + (size_t)b * N_ * PD_;
    float*       outb = out + (size_t)b * N_ * D_;

    convert_x_kernel<<<dim3(2048), blk, 0, stream>>>(xbp, xb);
    // QKV' = xb @ [Wq;Wk;Wv]^T   [4096 x 3072] bf16
    gemm_bf16_kernel<0><<<dim3(3072 / 128, N_ / 128), blk, 0, stream>>>(
        xb, D_, Wc, nullptr, QKVb, 3072, D_);
    // ctx partials via MFMA (16 chunks x 16 heads)
    ctx_mfma_kernel<<<dim3(16, H_), blk, 0, stream>>>(QKVb, posb, bk, partial);
    // reduce + /colsum + +bv + transpose -> ctx_t bf16
    ctx_finalize_kernel<<<dim3(H_), blk, 0, stream>>>(partial, bv, ctxt);
    // P @ ctx_t via MFMA -> writes into QKV V' slots
    attn_mfma_kernel<<<dim3(N_ / 64, H_), blk, 0, stream>>>(
        QKVb, posb, alpha, beta, bq, ctxt);
    // out = attn @ Wo^T + bo   (f32)
    gemm_bf16_kernel<1><<<dim3(1024 / 128, N_ / 128), blk, 0, stream>>>(
        QKVb + 2048, 3072, Woc, bo, outb, D_, D_);
  }
}

// Round 7
// 430.450 us; speedup vs baseline: 2.2496x; 1.5220x over previous
//
#include <hip/hip_runtime.h>
#include <cstddef>
#include <cstdint>

// Problem constants
#define NB_ 4
#define N_ 4096
#define D_ 1024
#define H_ 16
#define DH_ 64
#define PD_ 8
#define PS_ 4
#define F_ 72               // DH + PD
#define LST_ 104            // row stride for P and ctx_t (bank-friendly)
#define CTROWS_ 80          // ctx_t rows: 64 e + 1 ones + 15 zero
#define CTSZ_ (CTROWS_ * LST_)   // 8320 ushorts per (b,h) ctx_t
#define SLOT_ (F_ * DH_ + F_)    // 4680 floats per partial slot
#define M_ (NB_ * N_)            // 16384 rows total

typedef __attribute__((ext_vector_type(8))) short short8;
typedef __attribute__((ext_vector_type(4))) float f32x4;
typedef __attribute__((ext_vector_type(8))) unsigned short ushort8;

__device__ __forceinline__ unsigned short f2bf(float f) {
  uint32_t u = __builtin_bit_cast(uint32_t, f);
  u += 0x7FFFu + ((u >> 16) & 1u);          // RTNE
  return (unsigned short)(u >> 16);
}
__device__ __forceinline__ float bf2f(unsigned short h) {
  uint32_t u = ((uint32_t)h) << 16;
  return __builtin_bit_cast(float, u);
}

__device__ __forceinline__ void gload16(const void* g, void* l) {
  __builtin_amdgcn_global_load_lds((const __attribute__((address_space(1))) void*)g,
                                   (__attribute__((address_space(3))) void*)l, 16, 0, 0);
}

// ---------------- f32 -> bf16 conversion kernels -----------------------------
__global__ __launch_bounds__(256) void convert_x_kernel(
    const float* __restrict__ in, unsigned short* __restrict__ out)
{
  const int i = blockIdx.x * 256 + threadIdx.x;   // 8-elem group index
  const float4* p = (const float4*)in + (size_t)i * 2;
  const float4 a = p[0], b = p[1];
  ushort8 o;
  o[0] = f2bf(a.x); o[1] = f2bf(a.y); o[2] = f2bf(a.z); o[3] = f2bf(a.w);
  o[4] = f2bf(b.x); o[5] = f2bf(b.y); o[6] = f2bf(b.z); o[7] = f2bf(b.w);
  *(ushort8*)(out + (size_t)i * 8) = o;
}

// Wc rows: [0,1024)=Wq, [1024,2048)=Wk, [2048,3072)=Wv, [3072,4096)=Wo
__global__ __launch_bounds__(256) void convert_w_kernel(
    const float* __restrict__ Wq, const float* __restrict__ Wk,
    const float* __restrict__ Wv, const float* __restrict__ Wo,
    unsigned short* __restrict__ Wc)
{
  const int i = blockIdx.x * 256 + threadIdx.x;
  const size_t off = (size_t)i * 8;
  const float* src;
  if (off < (size_t)1048576)      src = Wq + off;
  else if (off < (size_t)2097152) src = Wk + (off - 1048576);
  else if (off < (size_t)3145728) src = Wv + (off - 2097152);
  else                            src = Wo + (off - 3145728);
  const float4 a = ((const float4*)src)[0], b = ((const float4*)src)[1];
  ushort8 o;
  o[0] = f2bf(a.x); o[1] = f2bf(a.y); o[2] = f2bf(a.z); o[3] = f2bf(a.w);
  o[4] = f2bf(b.x); o[5] = f2bf(b.y); o[6] = f2bf(b.z); o[7] = f2bf(b.w);
  *(ushort8*)(Wc + off) = o;
}

// ---------------- bf16 MFMA GEMM: C = A @ W^T (+ bias) -----------------------
// (hardware-verified rounds 3-4; + T1 XCD-aware block swizzle, grid%8==0)
template <int OUTMODE>
__global__ __launch_bounds__(256) void gemm_bf16_kernel(
    const unsigned short* __restrict__ A, int lda,
    const unsigned short* __restrict__ Wt,
    const float* __restrict__ bias,
    void* __restrict__ Cout, int ldc, int K)
{
  __shared__ unsigned short lds[2 * 128 * 64];   // A tile [0,8192), B tile [8192,16384)
  const int tid = threadIdx.x;
  const int lane = tid & 63;
  const int w = tid >> 6;
  const int wr = w >> 1, wc = w & 1;

  // T1: bijective XCD swizzle (total blocks divisible by 8 for all our grids).
  const int id  = blockIdx.y * gridDim.x + blockIdx.x;
  const int cpx = (gridDim.x * gridDim.y) >> 3;
  const int swz = (id & 7) * cpx + (id >> 3);
  const int m0 = (swz / gridDim.x) * 128;
  const int j0 = (swz % gridDim.x) * 128;

  const unsigned short* aSrc[4];
  const unsigned short* bSrc[4];
#pragma unroll
  for (int it = 0; it < 4; ++it) {
    const int u = it * 256 + tid;      // linear 16B slot in tile
    const int row = u >> 3, c = u & 7;
    const int ks = c ^ (row & 7);
    aSrc[it] = A  + (size_t)(m0 + row) * lda + ks * 8;
    bSrc[it] = Wt + (size_t)(j0 + row) * K   + ks * 8;
  }

  int aoff[4][2], boff[4][2];
#pragma unroll
  for (int m = 0; m < 4; ++m) {
#pragma unroll
    for (int s = 0; s < 2; ++s) {
      const int kslot = s * 4 + (lane >> 4);
      const int ra = wr * 64 + m * 16 + (lane & 15);
      aoff[m][s] = (ra * 8 + (kslot ^ (ra & 7))) * 8;
      const int rb = wc * 64 + m * 16 + (lane & 15);
      boff[m][s] = 8192 + (rb * 8 + (kslot ^ (rb & 7))) * 8;
    }
  }

  f32x4 acc[4][4];
#pragma unroll
  for (int m = 0; m < 4; ++m)
#pragma unroll
    for (int n = 0; n < 4; ++n) acc[m][n] = {0.f, 0.f, 0.f, 0.f};

  for (int k0 = 0; k0 < K; k0 += 64) {
    __syncthreads();
#pragma unroll
    for (int it = 0; it < 4; ++it) {
      gload16(aSrc[it] + k0, (void*)&lds[(size_t)(it * 256 + w * 64) * 8]);
      gload16(bSrc[it] + k0, (void*)&lds[8192 + (size_t)(it * 256 + w * 64) * 8]);
    }
    __syncthreads();
#pragma unroll
    for (int s = 0; s < 2; ++s) {
      short8 af[4], bfr[4];
#pragma unroll
      for (int m = 0; m < 4; ++m) af[m] = *(const short8*)&lds[aoff[m][s]];
#pragma unroll
      for (int n = 0; n < 4; ++n) bfr[n] = *(const short8*)&lds[boff[n][s]];
#pragma unroll
      for (int m = 0; m < 4; ++m)
#pragma unroll
        for (int n = 0; n < 4; ++n)
          acc[m][n] = __builtin_amdgcn_mfma_f32_16x16x32_bf16(af[m], bfr[n], acc[m][n], 0, 0, 0);
    }
  }

  const int rbase = (lane >> 4) * 4;
  const int cbase = lane & 15;
#pragma unroll
  for (int m = 0; m < 4; ++m) {
#pragma unroll
    for (int n = 0; n < 4; ++n) {
      const int col = j0 + wc * 64 + n * 16 + cbase;
      const float bj = (OUTMODE == 1) ? bias[col] : 0.f;
#pragma unroll
      for (int r = 0; r < 4; ++r) {
        const int rowi = m0 + wr * 64 + m * 16 + rbase + r;
        if (OUTMODE == 0)
          ((unsigned short*)Cout)[(size_t)rowi * ldc + col] = f2bf(acc[m][n][r]);
        else
          ((float*)Cout)[(size_t)rowi * ldc + col] = acc[m][n][r] + bj;
      }
    }
  }
}

// ---------- ctx via MFMA: per (bh,chunk) partial [Kexp^T @ V | colsum] -------
// blockIdx.y = bh (b*16+h), blockIdx.x = chunk (16 x 256 rows within batch).
__global__ __launch_bounds__(256) void ctx_mfma_kernel(
    const unsigned short* __restrict__ QKV, const float* __restrict__ pos,
    const float* __restrict__ bk, float* __restrict__ partial)
{
  const int bh = blockIdx.y, ch = blockIdx.x;
  const int bb = bh >> 4, h = bh & 15;
  const int tid = threadIdx.x;
  const int w = tid >> 6, lane = tid & 63;
  const int g = lane >> 4, c15 = lane & 15;
  const int n0 = bb * N_ + ch * 256 + w * 64;   // global row

  f32x4 acc[5][5];
#pragma unroll
  for (int dt = 0; dt < 5; ++dt)
#pragma unroll
    for (int ct = 0; ct < 5; ++ct) acc[dt][ct] = {0.f, 0.f, 0.f, 0.f};

  for (int kc = 0; kc < 2; ++kc) {
    const int nb = n0 + kc * 32 + g * 8;        // this lane's first row (j adds 0..7)
    const size_t rowb = (size_t)nb * 3072;

    short8 bf4[4];
#pragma unroll
    for (int et = 0; et < 4; ++et) {
      const unsigned short* vp = QKV + rowb + 2048 + h * 64 + et * 16 + c15;
      ushort8 t;
#pragma unroll
      for (int j = 0; j < 8; ++j) t[j] = vp[(size_t)j * 3072];
      bf4[et] = __builtin_bit_cast(short8, t);
    }
    ushort8 ot;
    const unsigned short one = (c15 == 0) ? (unsigned short)0x3F80 : (unsigned short)0;
#pragma unroll
    for (int j = 0; j < 8; ++j) ot[j] = one;
    const short8 onesf = __builtin_bit_cast(short8, ot);

#pragma unroll
    for (int dt = 0; dt < 5; ++dt) {
      const int d = dt * 16 + c15;
      ushort8 at;
      if (dt < 4) {                              // content dims: K' + bk, exp
        const float bkd = bk[h * F_ + d];
        const unsigned short* kp = QKV + rowb + 1024 + h * 64 + d;
#pragma unroll
        for (int j = 0; j < 8; ++j) at[j] = f2bf(__expf(bf2f(kp[(size_t)j * 3072]) + bkd));
      } else if (d < 72) {                       // pos dims: raw pos + bk, exp
        const float bkd = bk[h * F_ + d];
        const float* pp = pos + (size_t)nb * PD_ + (d - 64);
#pragma unroll
        for (int j = 0; j < 8; ++j) at[j] = f2bf(__expf(pp[(size_t)j * PD_] + bkd));
      } else {                                   // zero pad rows
#pragma unroll
        for (int j = 0; j < 8; ++j) at[j] = 0;
      }
      const short8 af = __builtin_bit_cast(short8, at);
#pragma unroll
      for (int ct = 0; ct < 4; ++ct)
        acc[dt][ct] = __builtin_amdgcn_mfma_f32_16x16x32_bf16(af, bf4[ct], acc[dt][ct], 0, 0, 0);
      acc[dt][4] = __builtin_amdgcn_mfma_f32_16x16x32_bf16(af, onesf, acc[dt][4], 0, 0, 0);
    }
  }

  // Cross-wave reduce in LDS. D-layout: row = dt*16 + g*4 + r, col = ct*16 + c15.
  __shared__ float red[80 * 80];
  const int rb = g * 4;
  for (int ww = 0; ww < 4; ++ww) {
    if (w == ww) {
#pragma unroll
      for (int dt = 0; dt < 5; ++dt)
#pragma unroll
        for (int ct = 0; ct < 5; ++ct)
#pragma unroll
          for (int r = 0; r < 4; ++r) {
            const int idx = (dt * 16 + rb + r) * 80 + ct * 16 + c15;
            if (ww == 0) red[idx] = acc[dt][ct][r];
            else         red[idx] += acc[dt][ct][r];
          }
    }
    __syncthreads();
  }
  float* pp = partial + (size_t)(bh * 16 + ch) * SLOT_;
  for (int idx = tid; idx < SLOT_; idx += 256)
    pp[idx] = (idx < 4608) ? red[(idx >> 6) * 80 + (idx & 63)]
                           : red[(idx - 4608) * 80 + 64];
}

// ---------- ctx finalize: reduce chunks, /colsum, +bv, transpose, bf16 -------
// blockIdx.x = bh. Writes ctx_t[bh][e][d], row 64 = ones (for qsum).
__global__ __launch_bounds__(256) void ctx_finalize_kernel(
    const float* __restrict__ partial, const float* __restrict__ bv,
    unsigned short* __restrict__ ctxt)
{
  const int bh = blockIdx.x;
  const int h = bh & 15;
  const int tid = threadIdx.x;
  __shared__ float num[F_ * DH_];
  __shared__ float cinv[F_];
  for (int idx = tid; idx < F_ * DH_; idx += 256) {
    float s = 0.f;
    for (int c = 0; c < 16; ++c) s += partial[(size_t)(bh * 16 + c) * SLOT_ + idx];
    num[idx] = s;
  }
  if (tid < F_) {
    float s = 0.f;
    for (int c = 0; c < 16; ++c) s += partial[(size_t)(bh * 16 + c) * SLOT_ + F_ * DH_ + tid];
    cinv[tid] = 1.0f / s;
  }
  __syncthreads();
  unsigned short* cp = ctxt + (size_t)bh * CTSZ_;
  for (int j = tid; j < CTSZ_; j += 256) {
    const int e = j / LST_, d = j - e * LST_;
    float v = 0.f;
    if (e < 64)       { if (d < F_) v = num[d * 64 + e] * cinv[d] + bv[h * 64 + e]; }
    else if (e == 64) { if (d < F_) v = 1.0f; }
    cp[j] = f2bf(v);
  }
}

// ---------- attention out via MFMA: P[64 x 96] @ ctx_t^T, qsum via ones-row --
// blockIdx.y = bh, blockIdx.x = 64-row chunk within batch.
// Writes result into QKV's dead V' slots (cols [2048,3072)).
__global__ __launch_bounds__(256) void attn_mfma_kernel(
    unsigned short* __restrict__ QKV, const float* __restrict__ pos,
    const float* __restrict__ alpha, const float* __restrict__ beta,
    const float* __restrict__ bq, const unsigned short* __restrict__ ctxt)
{
  const int bh = blockIdx.y;
  const int bb = bh >> 4, h = bh & 15;
  const int n0 = bb * N_ + blockIdx.x * 64;     // global row
  const int tid = threadIdx.x;
  __shared__ unsigned short P[64 * LST_];
  __shared__ unsigned short CT[CTROWS_ * LST_];
  __shared__ float bqs[F_];

  const unsigned short* cg = ctxt + (size_t)bh * CTSZ_;
  for (int idx = tid; idx < CTSZ_ / 8; idx += 256)
    *(ushort8*)&CT[idx * 8] = *(const ushort8*)&cg[idx * 8];
  if (tid < F_) bqs[tid] = bq[h * F_ + tid];
  __syncthreads();

  {  // build P: exp(q + bq) in bf16; rows = tokens, cols = d (96 zero-padded)
    const int row = tid >> 2, q4 = tid & 3;
    const unsigned short* qp = QKV + (size_t)(n0 + row) * 3072 + h * 64 + q4 * 16;
    const ushort8 a = *(const ushort8*)qp;
    const ushort8 b = *(const ushort8*)(qp + 8);
    ushort8 oa, ob;
#pragma unroll
    for (int j = 0; j < 8; ++j) {
      oa[j] = f2bf(__expf(bf2f(a[j]) + bqs[q4 * 16 + j]));
      ob[j] = f2bf(__expf(bf2f(b[j]) + bqs[q4 * 16 + 8 + j]));
    }
    *(ushort8*)&P[row * LST_ + q4 * 16] = oa;
    *(ushort8*)&P[row * LST_ + q4 * 16 + 8] = ob;
    // pos rotation pair s = q4
    const float p0 = pos[(size_t)(n0 + row) * PD_ + 2 * q4];
    const float p1 = pos[(size_t)(n0 + row) * PD_ + 2 * q4 + 1];
    const float al = alpha[h * PS_ + q4], be = beta[h * PS_ + q4];
    P[row * LST_ + 64 + 2 * q4]     = f2bf(__expf(al * p0 - be * p1 + bqs[64 + 2 * q4]));
    P[row * LST_ + 64 + 2 * q4 + 1] = f2bf(__expf(be * p0 + al * p1 + bqs[64 + 2 * q4 + 1]));
#pragma unroll
    for (int jj = 0; jj < 6; ++jj) P[row * LST_ + 72 + q4 * 6 + jj] = 0;  // k-pad
  }
  __syncthreads();

  const int w = tid >> 6, lane = tid & 63;
  const int g = lane >> 4, c15 = lane & 15;
  f32x4 acc[5];
#pragma unroll
  for (int ct = 0; ct < 5; ++ct) acc[ct] = {0.f, 0.f, 0.f, 0.f};
  short8 af[3];
#pragma unroll
  for (int ks = 0; ks < 3; ++ks)
    af[ks] = *(const short8*)&P[(w * 16 + c15) * LST_ + ks * 32 + g * 8];
#pragma unroll
  for (int ct = 0; ct < 5; ++ct) {
#pragma unroll
    for (int ks = 0; ks < 3; ++ks) {
      const short8 bfr = *(const short8*)&CT[(ct * 16 + c15) * LST_ + ks * 32 + g * 8];
      acc[ct] = __builtin_amdgcn_mfma_f32_16x16x32_bf16(af[ks], bfr, acc[ct], 0, 0, 0);
    }
  }
  // qsum lives in col-tile 4, col 64 (lanes with c15==0), rows g*4+r.
  float qinv[4];
#pragma unroll
  for (int r = 0; r < 4; ++r) {
    const float qs = __shfl(acc[4][r], lane & 48);
    qinv[r] = 1.0f / qs;
  }
#pragma unroll
  for (int ct = 0; ct < 4; ++ct) {
#pragma unroll
    for (int r = 0; r < 4; ++r) {
      const int rowi = n0 + w * 16 + g * 4 + r;
      QKV[(size_t)rowi * 3072 + 2048 + h * 64 + ct * 16 + c15] = f2bf(acc[ct][r] * qinv[r]);
    }
  }
}

// ------------------------------ launch ---------------------------------------
extern "C" void kernel_launch(void* const* d_in, const int* in_sizes, int n_in,
                              void* d_out, int out_size, void* d_ws, size_t ws_size,
                              hipStream_t stream) {
  const float* x     = (const float*)d_in[0];
  const float* pos   = (const float*)d_in[1];
  const float* Wq    = (const float*)d_in[2];
  const float* alpha = (const float*)d_in[3];
  const float* beta  = (const float*)d_in[4];
  const float* bq    = (const float*)d_in[5];
  const float* Wk    = (const float*)d_in[6];
  const float* bk    = (const float*)d_in[7];
  const float* Wv    = (const float*)d_in[8];
  const float* bv    = (const float*)d_in[9];
  const float* Wo    = (const float*)d_in[10];
  const float* bo    = (const float*)d_in[11];
  float* out = (float*)d_out;

  // Workspace (bytes), total ~163 MB (ws_size = 256 MiB, verified round 4).
  const size_t OFF_WC   = 0;                         // [4096][1024] bf16 (Wq|Wk|Wv|Wo)
  const size_t SZ_WC    = (size_t)4096 * 1024 * 2;
  const size_t OFF_XB   = OFF_WC + SZ_WC;            // [16384][1024] bf16
  const size_t SZ_XB    = (size_t)M_ * D_ * 2;
  const size_t OFF_QKV  = OFF_XB + SZ_XB;            // [16384][3072] bf16
  const size_t SZ_QKV   = (size_t)M_ * 3072 * 2;
  const size_t OFF_PART = OFF_QKV + SZ_QKV;          // f32 partials [64][16][SLOT_]
  const size_t SZ_PART  = (size_t)NB_ * H_ * 16 * SLOT_ * sizeof(float);
  const size_t OFF_CT   = OFF_PART + SZ_PART;        // ctx_t bf16 [64][80][104]
  const size_t SZ_CT    = (size_t)NB_ * H_ * CTSZ_ * 2;
  if (ws_size < OFF_CT + SZ_CT) return;

  char* ws = (char*)d_ws;
  unsigned short* Wc      = (unsigned short*)(ws + OFF_WC);
  unsigned short* Woc     = Wc + (size_t)3072 * 1024;
  unsigned short* xb      = (unsigned short*)(ws + OFF_XB);
  unsigned short* QKVb    = (unsigned short*)(ws + OFF_QKV);
  float*          partial = (float*)(ws + OFF_PART);
  unsigned short* ctxt    = (unsigned short*)(ws + OFF_CT);

  const dim3 blk(256);
  // weights -> bf16 (once per call)
  convert_w_kernel<<<dim3(2048), blk, 0, stream>>>(Wq, Wk, Wv, Wo, Wc);
  // x -> bf16, all batches
  convert_x_kernel<<<dim3(M_ * D_ / (256 * 8)), blk, 0, stream>>>(x, xb);
  // QKV' = xb @ [Wq;Wk;Wv]^T   [16384 x 3072] bf16
  gemm_bf16_kernel<0><<<dim3(3072 / 128, M_ / 128), blk, 0, stream>>>(
      xb, D_, Wc, nullptr, QKVb, 3072, D_);
  // ctx partials via MFMA (16 chunks x 64 bh)
  ctx_mfma_kernel<<<dim3(16, NB_ * H_), blk, 0, stream>>>(QKVb, pos, bk, partial);
  // reduce + /colsum + +bv + transpose -> ctx_t bf16
  ctx_finalize_kernel<<<dim3(NB_ * H_), blk, 0, stream>>>(partial, bv, ctxt);
  // P @ ctx_t via MFMA -> writes into QKV V' slots
  attn_mfma_kernel<<<dim3(N_ / 64, NB_ * H_), blk, 0, stream>>>(
      QKVb, pos, alpha, beta, bq, ctxt);
  // out = attn @ Wo^T + bo   (f32)
  gemm_bf16_kernel<1><<<dim3(1024 / 128, M_ / 128), blk, 0, stream>>>(
      QKVb + 2048, 3072, Woc, bo, out, D_, D_);
}

// Round 9
// 398.824 us; speedup vs baseline: 2.4280x; 1.0793x over previous
//
#include <hip/hip_runtime.h>
#include <cstddef>
#include <cstdint>

// Problem constants
#define NB_ 4
#define N_ 4096
#define D_ 1024
#define H_ 16
#define DH_ 64
#define PD_ 8
#define PS_ 4
#define F_ 72               // DH + PD
#define LST_ 104            // row stride for P and ctx_t (bank-friendly)
#define CTROWS_ 80          // ctx_t rows: 64 e + 1 ones + 15 zero
#define CTSZ_ (CTROWS_ * LST_)   // 8320 ushorts per (b,h) ctx_t
#define SLOT_ (F_ * DH_ + F_)    // 4680 floats per partial slot
#define M_ (NB_ * N_)            // 16384 rows total

typedef __attribute__((ext_vector_type(8))) short short8;
typedef __attribute__((ext_vector_type(4))) float f32x4;
typedef __attribute__((ext_vector_type(8))) unsigned short ushort8;

__device__ __forceinline__ unsigned short f2bf(float f) {
  uint32_t u = __builtin_bit_cast(uint32_t, f);
  u += 0x7FFFu + ((u >> 16) & 1u);          // RTNE
  return (unsigned short)(u >> 16);
}
__device__ __forceinline__ float bf2f(unsigned short h) {
  uint32_t u = ((uint32_t)h) << 16;
  return __builtin_bit_cast(float, u);
}

__device__ __forceinline__ void gload16(const void* g, void* l) {
  __builtin_amdgcn_global_load_lds((const __attribute__((address_space(1))) void*)g,
                                   (__attribute__((address_space(3))) void*)l, 16, 0, 0);
}

// ---------------- f32 -> bf16 conversion kernels -----------------------------
__global__ __launch_bounds__(256) void convert_x_kernel(
    const float* __restrict__ in, unsigned short* __restrict__ out)
{
  const int i = blockIdx.x * 256 + threadIdx.x;   // 8-elem group index
  const float4* p = (const float4*)in + (size_t)i * 2;
  const float4 a = p[0], b = p[1];
  ushort8 o;
  o[0] = f2bf(a.x); o[1] = f2bf(a.y); o[2] = f2bf(a.z); o[3] = f2bf(a.w);
  o[4] = f2bf(b.x); o[5] = f2bf(b.y); o[6] = f2bf(b.z); o[7] = f2bf(b.w);
  *(ushort8*)(out + (size_t)i * 8) = o;
}

// Wc rows: [0,1024)=Wq, [1024,2048)=Wk, [2048,3072)=Wv, [3072,4096)=Wo
__global__ __launch_bounds__(256) void convert_w_kernel(
    const float* __restrict__ Wq, const float* __restrict__ Wk,
    const float* __restrict__ Wv, const float* __restrict__ Wo,
    unsigned short* __restrict__ Wc)
{
  const int i = blockIdx.x * 256 + threadIdx.x;
  const size_t off = (size_t)i * 8;
  const float* src;
  if (off < (size_t)1048576)      src = Wq + off;
  else if (off < (size_t)2097152) src = Wk + (off - 1048576);
  else if (off < (size_t)3145728) src = Wv + (off - 2097152);
  else                            src = Wo + (off - 3145728);
  const float4 a = ((const float4*)src)[0], b = ((const float4*)src)[1];
  ushort8 o;
  o[0] = f2bf(a.x); o[1] = f2bf(a.y); o[2] = f2bf(a.z); o[3] = f2bf(a.w);
  o[4] = f2bf(b.x); o[5] = f2bf(b.y); o[6] = f2bf(b.z); o[7] = f2bf(b.w);
  *(ushort8*)(Wc + off) = o;
}

// ============ 256x256 BK=64 counted-vmcnt phase-scheduled bf16 GEMM ==========
// C = A @ W^T (+bias). 512 threads = 8 waves (2M x 4N); per-wave C = 128x64.
// LDS single-buffered 64KB: A[256][64] + B[256][64] bf16, XOR-swizzled
// (slot ^= row&7; inverse pre-applied on global src for global_load_lds).
// Per K-tile: 4 phases; phase q computes C-quadrant rows wm*128+q*32..+32
// over full BK=64 (16 MFMA). B is ds_read fully at phase 0 (dies -> restaged);
// A-quad q dies after phase q. Staging schedule per tile t:
//   ph0: A-q3(t)           ph1: B-h0(t+1), A-q0(t+1)
//   ph2: B-h1(t+1), A-q1(t+1)   ph3: A-q2(t+1)
// vmcnt at phase ends (audited via outstanding-queue simulation): 2, 4, 6, 1.
__device__ __forceinline__ void stage_quadA(
    const unsigned short* __restrict__ A, int lda, int m0, int q, int kofs,
    unsigned short* lbase, int w, int lane)
{
  const int rs  = (w < 4) ? (q * 32 + w * 8) : (128 + q * 32 + (w - 4) * 8);
  const int row = rs + (lane >> 3);
  const int ks  = (lane & 7) ^ (row & 7);
  gload16(A + (size_t)(m0 + row) * lda + kofs + ks * 8, lbase + rs * 64);
}

__device__ __forceinline__ void stage_halfB(
    const unsigned short* __restrict__ Wt, int K, int j0, int h, int kofs,
    unsigned short* lbase, int w, int lane)
{
#pragma unroll
  for (int l = 0; l < 2; ++l) {
    const int rs  = h * 128 + l * 64 + w * 8;
    const int row = rs + (lane >> 3);
    const int ks  = (lane & 7) ^ (row & 7);
    gload16(Wt + (size_t)(j0 + row) * K + kofs + ks * 8, lbase + rs * 64);
  }
}

template <int OUTMODE>
__global__ __launch_bounds__(512, 2) void gemm256_kernel(
    const unsigned short* __restrict__ A, int lda,
    const unsigned short* __restrict__ Wt,
    const float* __restrict__ bias,
    void* __restrict__ Cout, int ldc, int K)
{
  __shared__ unsigned short lds2[32768];   // A: [0,16384), B: [16384,32768)
  unsigned short* LA = lds2;
  unsigned short* LB = lds2 + 16384;
  const int tid = threadIdx.x, lane = tid & 63, w = tid >> 6;
  const int wm = w >> 2, wn = w & 3;

  // T1: bijective XCD swizzle (grid sizes 768 / 256, both % 8 == 0).
  const int id  = blockIdx.y * gridDim.x + blockIdx.x;
  const int cpx = (gridDim.x * gridDim.y) >> 3;
  const int swz = (id & 7) * cpx + (id >> 3);
  const int m0 = (swz / gridDim.x) * 256;
  const int j0 = (swz % gridDim.x) * 256;

  const int NT = K >> 6;

  f32x4 acc[8][4];
#pragma unroll
  for (int mi = 0; mi < 8; ++mi)
#pragma unroll
    for (int n = 0; n < 4; ++n) acc[mi][n] = {0.f, 0.f, 0.f, 0.f};

  // Prologue: stage tile 0's B0,B1,q0,q1,q2; full drain (one-time).
  stage_halfB(Wt, K, j0, 0, 0, LB, w, lane);
  stage_halfB(Wt, K, j0, 1, 0, LB, w, lane);
  stage_quadA(A, lda, m0, 0, 0, LA, w, lane);
  stage_quadA(A, lda, m0, 1, 0, LA, w, lane);
  stage_quadA(A, lda, m0, 2, 0, LA, w, lane);
  asm volatile("s_waitcnt vmcnt(0)" ::: "memory");
  __builtin_amdgcn_s_barrier();

  short8 bf[4][2];

  for (int t = 0; t < NT; ++t) {
    const int k0 = t << 6, kn = k0 + 64;
    const bool more = (t + 1 < NT);
#pragma unroll
    for (int q = 0; q < 4; ++q) {
      // ---- region A: ds_reads + stage issues + counted vmcnt + barrier ----
      if (q == 0) {
#pragma unroll
        for (int n = 0; n < 4; ++n) {
          const int rb = wn * 64 + n * 16 + (lane & 15);
#pragma unroll
          for (int s = 0; s < 2; ++s) {
            const int sl = (s * 4 + (lane >> 4)) ^ (rb & 7);
            bf[n][s] = *(const short8*)&LB[rb * 64 + sl * 8];
          }
        }
      }
      short8 af[2][2];
      const int ra0 = wm * 128 + q * 32 + (lane & 15);
#pragma unroll
      for (int f = 0; f < 2; ++f) {
        const int ra = ra0 + f * 16;
#pragma unroll
        for (int s = 0; s < 2; ++s) {
          const int sl = (s * 4 + (lane >> 4)) ^ (ra & 7);
          af[f][s] = *(const short8*)&LA[ra * 64 + sl * 8];
        }
      }
      if (q == 0) stage_quadA(A, lda, m0, 3, k0, LA, w, lane);
      if (q == 1 && more) { stage_halfB(Wt, K, j0, 0, kn, LB, w, lane);
                            stage_quadA(A, lda, m0, 0, kn, LA, w, lane); }
      if (q == 2 && more) { stage_halfB(Wt, K, j0, 1, kn, LB, w, lane);
                            stage_quadA(A, lda, m0, 1, kn, LA, w, lane); }
      if (q == 3 && more)   stage_quadA(A, lda, m0, 2, kn, LA, w, lane);

      if (q == 0) {
        asm volatile("s_waitcnt vmcnt(2)" ::: "memory");
      } else if (q == 1) {
        if (more) asm volatile("s_waitcnt vmcnt(4)" ::: "memory");
        else      asm volatile("s_waitcnt vmcnt(1)" ::: "memory");
      } else if (q == 2) {
        if (more) asm volatile("s_waitcnt vmcnt(6)" ::: "memory");
        else      asm volatile("s_waitcnt vmcnt(0)" ::: "memory");
      } else {
        if (more) asm volatile("s_waitcnt vmcnt(1)" ::: "memory");
      }
      __builtin_amdgcn_s_barrier();

      // ---- region B: MFMA cluster ----
      asm volatile("s_waitcnt lgkmcnt(0)" ::: "memory");
      __builtin_amdgcn_sched_barrier(0);
      __builtin_amdgcn_s_setprio(1);
#pragma unroll
      for (int f = 0; f < 2; ++f) {
#pragma unroll
        for (int n = 0; n < 4; ++n) {
          acc[q * 2 + f][n] = __builtin_amdgcn_mfma_f32_16x16x32_bf16(
              af[f][0], bf[n][0], acc[q * 2 + f][n], 0, 0, 0);
          acc[q * 2 + f][n] = __builtin_amdgcn_mfma_f32_16x16x32_bf16(
              af[f][1], bf[n][1], acc[q * 2 + f][n], 0, 0, 0);
        }
      }
      __builtin_amdgcn_s_setprio(0);
      __builtin_amdgcn_s_barrier();
    }
  }

  // Epilogue. C/D layout (m89-verified): row=(lane>>4)*4+reg, col=lane&15.
  const int rbase = (lane >> 4) * 4;
  const int cbase = lane & 15;
#pragma unroll
  for (int q = 0; q < 4; ++q) {
#pragma unroll
    for (int f = 0; f < 2; ++f) {
#pragma unroll
      for (int n = 0; n < 4; ++n) {
        const int col = j0 + wn * 64 + n * 16 + cbase;
        const float bj = (OUTMODE == 1) ? bias[col] : 0.f;
#pragma unroll
        for (int r = 0; r < 4; ++r) {
          const int rowi = m0 + wm * 128 + q * 32 + f * 16 + rbase + r;
          if (OUTMODE == 0)
            ((unsigned short*)Cout)[(size_t)rowi * ldc + col] =
                f2bf(acc[q * 2 + f][n][r]);
          else
            ((float*)Cout)[(size_t)rowi * ldc + col] = acc[q * 2 + f][n][r] + bj;
        }
      }
    }
  }
}

// ---------- ctx via MFMA: per (bh,chunk) partial [Kexp^T @ V | colsum] -------
// blockIdx.y = bh (b*16+h), blockIdx.x = chunk (16 x 256 rows within batch).
__global__ __launch_bounds__(256) void ctx_mfma_kernel(
    const unsigned short* __restrict__ QKV, const float* __restrict__ pos,
    const float* __restrict__ bk, float* __restrict__ partial)
{
  const int bh = blockIdx.y, ch = blockIdx.x;
  const int bb = bh >> 4, h = bh & 15;
  const int tid = threadIdx.x;
  const int w = tid >> 6, lane = tid & 63;
  const int g = lane >> 4, c15 = lane & 15;
  const int n0 = bb * N_ + ch * 256 + w * 64;   // global row

  f32x4 acc[5][5];
#pragma unroll
  for (int dt = 0; dt < 5; ++dt)
#pragma unroll
    for (int ct = 0; ct < 5; ++ct) acc[dt][ct] = {0.f, 0.f, 0.f, 0.f};

  for (int kc = 0; kc < 2; ++kc) {
    const int nb = n0 + kc * 32 + g * 8;        // this lane's first row (j adds 0..7)
    const size_t rowb = (size_t)nb * 3072;

    short8 bf4[4];
#pragma unroll
    for (int et = 0; et < 4; ++et) {
      const unsigned short* vp = QKV + rowb + 2048 + h * 64 + et * 16 + c15;
      ushort8 t;
#pragma unroll
      for (int j = 0; j < 8; ++j) t[j] = vp[(size_t)j * 3072];
      bf4[et] = __builtin_bit_cast(short8, t);
    }
    ushort8 ot;
    const unsigned short one = (c15 == 0) ? (unsigned short)0x3F80 : (unsigned short)0;
#pragma unroll
    for (int j = 0; j < 8; ++j) ot[j] = one;
    const short8 onesf = __builtin_bit_cast(short8, ot);

#pragma unroll
    for (int dt = 0; dt < 5; ++dt) {
      const int d = dt * 16 + c15;
      ushort8 at;
      if (dt < 4) {                              // content dims: K' + bk, exp
        const float bkd = bk[h * F_ + d];
        const unsigned short* kp = QKV + rowb + 1024 + h * 64 + d;
#pragma unroll
        for (int j = 0; j < 8; ++j) at[j] = f2bf(__expf(bf2f(kp[(size_t)j * 3072]) + bkd));
      } else if (d < 72) {                       // pos dims: raw pos + bk, exp
        const float bkd = bk[h * F_ + d];
        const float* pp = pos + (size_t)nb * PD_ + (d - 64);
#pragma unroll
        for (int j = 0; j < 8; ++j) at[j] = f2bf(__expf(pp[(size_t)j * PD_] + bkd));
      } else {                                   // zero pad rows
#pragma unroll
        for (int j = 0; j < 8; ++j) at[j] = 0;
      }
      const short8 af = __builtin_bit_cast(short8, at);
#pragma unroll
      for (int ct = 0; ct < 4; ++ct)
        acc[dt][ct] = __builtin_amdgcn_mfma_f32_16x16x32_bf16(af, bf4[ct], acc[dt][ct], 0, 0, 0);
      acc[dt][4] = __builtin_amdgcn_mfma_f32_16x16x32_bf16(af, onesf, acc[dt][4], 0, 0, 0);
    }
  }

  // Cross-wave reduce in LDS. D-layout: row = dt*16 + g*4 + r, col = ct*16 + c15.
  __shared__ float red[80 * 80];
  const int rb = g * 4;
  for (int ww = 0; ww < 4; ++ww) {
    if (w == ww) {
#pragma unroll
      for (int dt = 0; dt < 5; ++dt)
#pragma unroll
        for (int ct = 0; ct < 5; ++ct)
#pragma unroll
          for (int r = 0; r < 4; ++r) {
            const int idx = (dt * 16 + rb + r) * 80 + ct * 16 + c15;
            if (ww == 0) red[idx] = acc[dt][ct][r];
            else         red[idx] += acc[dt][ct][r];
          }
    }
    __syncthreads();
  }
  float* pp = partial + (size_t)(bh * 16 + ch) * SLOT_;
  for (int idx = tid; idx < SLOT_; idx += 256)
    pp[idx] = (idx < 4608) ? red[(idx >> 6) * 80 + (idx & 63)]
                           : red[(idx - 4608) * 80 + 64];
}

// ---------- ctx finalize: reduce chunks, /colsum, +bv, transpose, bf16 -------
// blockIdx.x = bh. Writes ctx_t[bh][e][d], row 64 = ones (for qsum).
__global__ __launch_bounds__(256) void ctx_finalize_kernel(
    const float* __restrict__ partial, const float* __restrict__ bv,
    unsigned short* __restrict__ ctxt)
{
  const int bh = blockIdx.x;
  const int h = bh & 15;
  const int tid = threadIdx.x;
  __shared__ float num[F_ * DH_];
  __shared__ float cinv[F_];
  for (int idx = tid; idx < F_ * DH_; idx += 256) {
    float s = 0.f;
    for (int c = 0; c < 16; ++c) s += partial[(size_t)(bh * 16 + c) * SLOT_ + idx];
    num[idx] = s;
  }
  if (tid < F_) {
    float s = 0.f;
    for (int c = 0; c < 16; ++c) s += partial[(size_t)(bh * 16 + c) * SLOT_ + F_ * DH_ + tid];
    cinv[tid] = 1.0f / s;
  }
  __syncthreads();
  unsigned short* cp = ctxt + (size_t)bh * CTSZ_;
  for (int j = tid; j < CTSZ_; j += 256) {
    const int e = j / LST_, d = j - e * LST_;
    float v = 0.f;
    if (e < 64)       { if (d < F_) v = num[d * 64 + e] * cinv[d] + bv[h * 64 + e]; }
    else if (e == 64) { if (d < F_) v = 1.0f; }
    cp[j] = f2bf(v);
  }
}

// ---------- attention out via MFMA: P[64 x 96] @ ctx_t^T, qsum via ones-row --
// blockIdx.y = bh, blockIdx.x = 64-row chunk within batch.
// Writes result into QKV's dead V' slots (cols [2048,3072)).
__global__ __launch_bounds__(256) void attn_mfma_kernel(
    unsigned short* __restrict__ QKV, const float* __restrict__ pos,
    const float* __restrict__ alpha, const float* __restrict__ beta,
    const float* __restrict__ bq, const unsigned short* __restrict__ ctxt)
{
  const int bh = blockIdx.y;
  const int bb = bh >> 4, h = bh & 15;
  const int n0 = bb * N_ + blockIdx.x * 64;     // global row
  const int tid = threadIdx.x;
  __shared__ unsigned short P[64 * LST_];
  __shared__ unsigned short CT[CTROWS_ * LST_];
  __shared__ float bqs[F_];

  const unsigned short* cg = ctxt + (size_t)bh * CTSZ_;
  for (int idx = tid; idx < CTSZ_ / 8; idx += 256)
    *(ushort8*)&CT[idx * 8] = *(const ushort8*)&cg[idx * 8];
  if (tid < F_) bqs[tid] = bq[h * F_ + tid];
  __syncthreads();

  {  // build P: exp(q + bq) in bf16; rows = tokens, cols = d (96 zero-padded)
    const int row = tid >> 2, q4 = tid & 3;
    const unsigned short* qp = QKV + (size_t)(n0 + row) * 3072 + h * 64 + q4 * 16;
    const ushort8 a = *(const ushort8*)qp;
    const ushort8 b = *(const ushort8*)(qp + 8);
    ushort8 oa, ob;
#pragma unroll
    for (int j = 0; j < 8; ++j) {
      oa[j] = f2bf(__expf(bf2f(a[j]) + bqs[q4 * 16 + j]));
      ob[j] = f2bf(__expf(bf2f(b[j]) + bqs[q4 * 16 + 8 + j]));
    }
    *(ushort8*)&P[row * LST_ + q4 * 16] = oa;
    *(ushort8*)&P[row * LST_ + q4 * 16 + 8] = ob;
    // pos rotation pair s = q4
    const float p0 = pos[(size_t)(n0 + row) * PD_ + 2 * q4];
    const float p1 = pos[(size_t)(n0 + row) * PD_ + 2 * q4 + 1];
    const float al = alpha[h * PS_ + q4], be = beta[h * PS_ + q4];
    P[row * LST_ + 64 + 2 * q4]     = f2bf(__expf(al * p0 - be * p1 + bqs[64 + 2 * q4]));
    P[row * LST_ + 64 + 2 * q4 + 1] = f2bf(__expf(be * p0 + al * p1 + bqs[64 + 2 * q4 + 1]));
#pragma unroll
    for (int jj = 0; jj < 6; ++jj) P[row * LST_ + 72 + q4 * 6 + jj] = 0;  // k-pad
  }
  __syncthreads();

  const int w = tid >> 6, lane = tid & 63;
  const int g = lane >> 4, c15 = lane & 15;
  f32x4 acc[5];
#pragma unroll
  for (int ct = 0; ct < 5; ++ct) acc[ct] = {0.f, 0.f, 0.f, 0.f};
  short8 af[3];
#pragma unroll
  for (int ks = 0; ks < 3; ++ks)
    af[ks] = *(const short8*)&P[(w * 16 + c15) * LST_ + ks * 32 + g * 8];
#pragma unroll
  for (int ct = 0; ct < 5; ++ct) {
#pragma unroll
    for (int ks = 0; ks < 3; ++ks) {
      const short8 bfr = *(const short8*)&CT[(ct * 16 + c15) * LST_ + ks * 32 + g * 8];
      acc[ct] = __builtin_amdgcn_mfma_f32_16x16x32_bf16(af[ks], bfr, acc[ct], 0, 0, 0);
    }
  }
  // qsum lives in col-tile 4, col 64 (lanes with c15==0), rows g*4+r.
  float qinv[4];
#pragma unroll
  for (int r = 0; r < 4; ++r) {
    const float qs = __shfl(acc[4][r], lane & 48);
    qinv[r] = 1.0f / qs;
  }
#pragma unroll
  for (int ct = 0; ct < 4; ++ct) {
#pragma unroll
    for (int r = 0; r < 4; ++r) {
      const int rowi = n0 + w * 16 + g * 4 + r;
      QKV[(size_t)rowi * 3072 + 2048 + h * 64 + ct * 16 + c15] = f2bf(acc[ct][r] * qinv[r]);
    }
  }
}

// ------------------------------ launch ---------------------------------------
extern "C" void kernel_launch(void* const* d_in, const int* in_sizes, int n_in,
                              void* d_out, int out_size, void* d_ws, size_t ws_size,
                              hipStream_t stream) {
  const float* x     = (const float*)d_in[0];
  const float* pos   = (const float*)d_in[1];
  const float* Wq    = (const float*)d_in[2];
  const float* alpha = (const float*)d_in[3];
  const float* beta  = (const float*)d_in[4];
  const float* bq    = (const float*)d_in[5];
  const float* Wk    = (const float*)d_in[6];
  const float* bk    = (const float*)d_in[7];
  const float* Wv    = (const float*)d_in[8];
  const float* bv    = (const float*)d_in[9];
  const float* Wo    = (const float*)d_in[10];
  const float* bo    = (const float*)d_in[11];
  float* out = (float*)d_out;

  // Workspace (bytes), total ~163 MB (ws_size = 256 MiB, verified round 4/7).
  const size_t OFF_WC   = 0;                         // [4096][1024] bf16 (Wq|Wk|Wv|Wo)
  const size_t SZ_WC    = (size_t)4096 * 1024 * 2;
  const size_t OFF_XB   = OFF_WC + SZ_WC;            // [16384][1024] bf16
  const size_t SZ_XB    = (size_t)M_ * D_ * 2;
  const size_t OFF_QKV  = OFF_XB + SZ_XB;            // [16384][3072] bf16
  const size_t SZ_QKV   = (size_t)M_ * 3072 * 2;
  const size_t OFF_PART = OFF_QKV + SZ_QKV;          // f32 partials [64][16][SLOT_]
  const size_t SZ_PART  = (size_t)NB_ * H_ * 16 * SLOT_ * sizeof(float);
  const size_t OFF_CT   = OFF_PART + SZ_PART;        // ctx_t bf16 [64][80][104]
  const size_t SZ_CT    = (size_t)NB_ * H_ * CTSZ_ * 2;
  if (ws_size < OFF_CT + SZ_CT) return;

  char* ws = (char*)d_ws;
  unsigned short* Wc      = (unsigned short*)(ws + OFF_WC);
  unsigned short* Woc     = Wc + (size_t)3072 * 1024;
  unsigned short* xb      = (unsigned short*)(ws + OFF_XB);
  unsigned short* QKVb    = (unsigned short*)(ws + OFF_QKV);
  float*          partial = (float*)(ws + OFF_PART);
  unsigned short* ctxt    = (unsigned short*)(ws + OFF_CT);

  const dim3 blk(256);
  const dim3 blk512(512);
  // weights -> bf16 (once per call)
  convert_w_kernel<<<dim3(2048), blk, 0, stream>>>(Wq, Wk, Wv, Wo, Wc);
  // x -> bf16, all batches
  convert_x_kernel<<<dim3(M_ * D_ / (256 * 8)), blk, 0, stream>>>(x, xb);
  // QKV' = xb @ [Wq;Wk;Wv]^T   [16384 x 3072] bf16  (256^2 phase-scheduled)
  gemm256_kernel<0><<<dim3(3072 / 256, M_ / 256), blk512, 0, stream>>>(
      xb, D_, Wc, nullptr, QKVb, 3072, D_);
  // ctx partials via MFMA (16 chunks x 64 bh)
  ctx_mfma_kernel<<<dim3(16, NB_ * H_), blk, 0, stream>>>(QKVb, pos, bk, partial);
  // reduce + /colsum + +bv + transpose -> ctx_t bf16
  ctx_finalize_kernel<<<dim3(NB_ * H_), blk, 0, stream>>>(partial, bv, ctxt);
  // P @ ctx_t via MFMA -> writes into QKV V' slots
  attn_mfma_kernel<<<dim3(N_ / 64, NB_ * H_), blk, 0, stream>>>(
      QKVb, pos, alpha, beta, bq, ctxt);
  // out = attn @ Wo^T + bo   (f32)  (256^2 phase-scheduled)
  gemm256_kernel<1><<<dim3(1024 / 256, M_ / 256), blk512, 0, stream>>>(
      QKVb + 2048, 3072, Woc, bo, out, D_, D_);
}